// Round 7
// baseline (213.722 us; speedup 1.0000x reference)
//
#include <hip/hip_runtime.h>
#include <math.h>

#define T_LEN 2048
#define NF    16
#define NTH   256
#define NOUT  3146
#define PI_F  3.14159265358979323846f

// ---------------- wave reductions (wave = 64) ----------------
__device__ __forceinline__ float wred_sum(float v) {
  v += __shfl_down(v, 32); v += __shfl_down(v, 16); v += __shfl_down(v, 8);
  v += __shfl_down(v, 4);  v += __shfl_down(v, 2);  v += __shfl_down(v, 1);
  return v;
}
__device__ __forceinline__ float wred_min(float v) {
  v = fminf(v, __shfl_down(v, 32)); v = fminf(v, __shfl_down(v, 16)); v = fminf(v, __shfl_down(v, 8));
  v = fminf(v, __shfl_down(v, 4));  v = fminf(v, __shfl_down(v, 2));  v = fminf(v, __shfl_down(v, 1));
  return v;
}
__device__ __forceinline__ float wred_max(float v) {
  v = fmaxf(v, __shfl_down(v, 32)); v = fmaxf(v, __shfl_down(v, 16)); v = fmaxf(v, __shfl_down(v, 8));
  v = fmaxf(v, __shfl_down(v, 4));  v = fmaxf(v, __shfl_down(v, 2));  v = fmaxf(v, __shfl_down(v, 1));
  return v;
}

// batched block sum: N values, 2 barriers total
template<int N>
__device__ __forceinline__ void block_sum_n(float (&v)[N], float* redw, float* res, int tid) {
  const int wave = tid >> 6;
#pragma unroll
  for (int j = 0; j < N; j++) {
    float s = wred_sum(v[j]);
    if ((tid & 63) == 0) redw[j * 4 + wave] = s;
  }
  __syncthreads();
  if (tid < N) res[tid] = redw[tid * 4] + redw[tid * 4 + 1] + redw[tid * 4 + 2] + redw[tid * 4 + 3];
  __syncthreads();
}

// agg4 over 9 register values
__device__ __forceinline__ void agg4_9(const float* v, float* om, float* ov, float* os, float* ok) {
  const float fn = 9.0f;
  float s = 0.f;
#pragma unroll
  for (int i = 0; i < 9; i++) s += v[i];
  float m = s / fn;
  float c2 = 0.f, c3 = 0.f, c4 = 0.f;
#pragma unroll
  for (int i = 0; i < 9; i++) {
    float c = v[i] - m; float cc = c * c;
    c2 += cc; c3 += cc * c; c4 += cc * cc;
  }
  float var = c2 / fn;
  float sd = (var > 0.f) ? sqrtf(var) : 0.f;
  float sk = (sd > 0.f) ? fn / ((fn - 1.f) * (fn - 2.f)) * (c3 / (sd * sd * sd)) : 0.f;
  float k22 = c2 * c2;
  float al = fn * (fn + 1.f) * (fn - 1.f) / ((fn - 2.f) * (fn - 3.f));
  float ku = ((k22 > 0.f) ? al * c4 / k22 : 0.f)
             - 3.f * (fn - 1.f) * (fn - 1.f) / ((fn - 2.f) * (fn - 3.f));
  *om = m; *ov = var; *os = sk; *ok = ku;
}

__device__ __forceinline__ float ord2f(unsigned int u) {
  unsigned int v = (u & 0x80000000u) ? (u ^ 0x80000000u) : ~u;
  return __uint_as_float(v);
}
__device__ __forceinline__ unsigned int f2ord(float v) {
  unsigned int u = __float_as_uint(v);
  return (u & 0x80000000u) ? ~u : (u | 0x80000000u);
}

// fast atan2 (deg-2 poly, max err ~0.006 rad; output threshold is 50.24 absolute)
__device__ __forceinline__ float fast_atan2f(float y, float x) {
  float ay = fabsf(y), ax = fabsf(x);
  float mx = fmaxf(ax, ay), mn = fminf(ax, ay);
  if (mx == 0.f) return 0.f;
  float t = __fdividef(mn, mx);
  float s = t * t;
  float p = fmaf(s, fmaf(s, 0.079331f, -0.288679f), 0.995354f);
  float r = t * p;
  if (ay > ax) r = 1.57079632679f - r;
  if (x < 0.f) r = PI_F - r;
  return (y < 0.f) ? -r : r;
}

__global__ __launch_bounds__(NTH)
void ts_feat_kernel(const float* __restrict__ x, float* __restrict__ out, int gpx) {
  __shared__ __align__(16) float a[T_LEN];        // series; later zr=a[0..1023], zi=a[1024..2047]
  __shared__ __align__(16) unsigned int U[2048];  // radix hist; later cos[1024]+sin[1024]
  __shared__ float redw[96];
  __shared__ float res[24];
  __shared__ unsigned int selres[8];
  __shared__ unsigned int wtot[4];

  float* zr = a;
  float* zi = a + 1024;
  float* Tc = (float*)U;
  float* Ts = (float*)U + 1024;

  const int tid = threadIdx.x;
  const int lane = tid & 63;
  const int wave = tid >> 6;
  int b, f;
  {
    int i = blockIdx.x;
    if (gpx > 0) { int xc = i & 7; int slot = i >> 3; b = xc * gpx + (slot >> 4); f = slot & 15; }
    else { b = i >> 4; f = i & 15; }
  }
  const float* xp = x + ((size_t)b * T_LEN) * NF + f;
  float* op = out + (size_t)(b * NF + f) * NOUT;
  const float fT = (float)T_LEN;

  // ---- zero full 2048-bin histogram ----
#pragma unroll
  for (int k = 0; k < 8; k++) U[tid + k * NTH] = 0u;

  // ---- phase 1: load; raw power sums; min/max; keys ----
  unsigned int key[8];
  float s1 = 0.f, s2 = 0.f, s3 = 0.f, s4 = 0.f, mn = 3.4e38f, mx = -3.4e38f;
#pragma unroll
  for (int k = 0; k < 8; k++) {
    int t = tid + k * NTH;
    float v = xp[(size_t)t * NF];
    a[t] = v;
    key[k] = f2ord(v);
    float v2 = v * v;
    s1 += v; s2 += v2; s3 += v2 * v; s4 += v2 * v2;
    mn = fminf(mn, v); mx = fmaxf(mx, v);
  }
  s1 = wred_sum(s1); s2 = wred_sum(s2); s3 = wred_sum(s3); s4 = wred_sum(s4);
  mn = wred_min(mn); mx = wred_max(mx);
  if (lane == 0) {
    redw[wave] = s1; redw[4 + wave] = s2; redw[8 + wave] = s3; redw[12 + wave] = s4;
    redw[16 + wave] = mn; redw[20 + wave] = mx;
  }
  __syncthreads();  // B1: U zeroed, a[] written, redw partials

  // round-A histogram: 11-bit digit into shared 2048-bin hist
#pragma unroll
  for (int k = 0; k < 8; k++) atomicAdd(&U[key[k] >> 21], 1u);
  if (tid == 0) {
    res[0] = redw[0] + redw[1] + redw[2] + redw[3];
    res[1] = redw[4] + redw[5] + redw[6] + redw[7];
    res[2] = redw[8] + redw[9] + redw[10] + redw[11];
    res[3] = redw[12] + redw[13] + redw[14] + redw[15];
    res[4] = fminf(fminf(redw[16], redw[17]), fminf(redw[18], redw[19]));
    res[5] = fmaxf(fmaxf(redw[20], redw[21]), fmaxf(redw[22], redw[23]));
  }
  __syncthreads();  // B2: hist + stats visible

  float S1 = res[0], S2v = res[1], S3v = res[2], S4v = res[3], MN = res[4], MX = res[5];
  float mean = S1 / fT;
  float maxabs = fmaxf(-MN, MX);
  float rms = sqrtf(fmaxf(S2v / fT, 0.f));

  // ---- round-A scan: thread owns 8 bins ----
  uint4 h0 = ((const uint4*)U)[2 * tid];
  uint4 h1 = ((const uint4*)U)[2 * tid + 1];
  if (tid < 48) {  // self-zero bins 0..383 for rounds B-D (only owner ever reads them)
    uint4 z; z.x = 0u; z.y = 0u; z.z = 0u; z.w = 0u;
    ((uint4*)U)[2 * tid] = z; ((uint4*)U)[2 * tid + 1] = z;
  }
  unsigned c1 = h0.x, c2 = c1 + h0.y, c3 = c2 + h0.z, c4 = c3 + h0.w;
  unsigned c5 = c4 + h1.x, c6 = c5 + h1.y, c7 = c6 + h1.z, tot = c7 + h1.w;
  unsigned sc = tot;
#pragma unroll
  for (int off = 1; off < 64; off <<= 1) {
    unsigned n = __shfl_up(sc, off);
    if (lane >= off) sc += n;
  }
  if (lane == 63) wtot[wave] = sc;

  // phase-2 window: diffs + lags + window-C2 (ac path bit-identical to r5/r6)
  float v13[13];
  {
    const int base = tid * 8;
    const float4* a4 = (const float4*)a;
    float4 w0 = a4[tid*2], w1 = a4[tid*2+1];
    int i2 = (base + 11 < T_LEN) ? tid*2+2 : 0;
    int i3 = (base + 15 < T_LEN) ? tid*2+3 : 0;
    float4 w2 = a4[i2], w3 = a4[i3];
    bool ok2 = (base + 11 < T_LEN), ok3 = (base + 15 < T_LEN);
    float r[17];
    r[0]=w0.x; r[1]=w0.y; r[2]=w0.z; r[3]=w0.w;
    r[4]=w1.x; r[5]=w1.y; r[6]=w1.z; r[7]=w1.w;
    r[8]  = ok2 ? w2.x : mean; r[9]  = ok2 ? w2.y : mean; r[10] = ok2 ? w2.z : mean; r[11] = ok2 ? w2.w : mean;
    r[12] = ok3 ? w3.x : mean; r[13] = ok3 ? w3.y : mean; r[14] = ok3 ? w3.z : mean; r[15] = ok3 ? w3.w : mean;
    r[16] = (base + 16 < T_LEN) ? a[base + 16] : mean;
    float cw[17];
#pragma unroll
    for (int j = 0; j < 17; j++) cw[j] = r[j] - mean;
#pragma unroll
    for (int j = 0; j < 13; j++) v13[j] = 0.f;
#pragma unroll
    for (int j = 0; j < 8; j++) {
      if (base + j < T_LEN - 2) {
        float d = r[j+1] - r[j+2];
        v13[0] += d; v13[1] += fabsf(d); v13[2] += d * d;
      }
    }
#pragma unroll
    for (int l = 1; l <= 9; l++) {
#pragma unroll
      for (int j = 0; j < 8; j++) {
        v13[2 + l] += cw[j] * cw[j + l];  // OOB cw == 0
      }
    }
#pragma unroll
    for (int j = 0; j < 8; j++) v13[12] += cw[j] * cw[j];
  }
  // manual block_sum_n<13> part 1 (merged with radix barriers)
  {
#pragma unroll
    for (int j = 0; j < 13; j++) {
      float s = wred_sum(v13[j]);
      if (lane == 0) redw[j * 4 + wave] = s;
    }
  }
  __syncthreads();  // B3: wtot + v13 partials visible

  if (tid < 13) res[tid] = redw[tid*4] + redw[tid*4+1] + redw[tid*4+2] + redw[tid*4+3];
  // round-A pick (predicated; ≤3 threads hit)
  {
    unsigned base0 = 0;
    if (wave > 0) base0 += wtot[0];
    if (wave > 1) base0 += wtot[1];
    if (wave > 2) base0 += wtot[2];
    unsigned excl = base0 + sc - tot;
#pragma unroll
    for (int j = 0; j < 3; j++) {
      const unsigned rj = 512u * (unsigned)(j + 1);
      if (rj >= excl && rj < excl + tot) {
        unsigned r = rj - excl;
        unsigned bin, resid;
        if      (r < c1) { bin = 0u; resid = r; }
        else if (r < c2) { bin = 1u; resid = r - c1; }
        else if (r < c3) { bin = 2u; resid = r - c2; }
        else if (r < c4) { bin = 3u; resid = r - c3; }
        else if (r < c5) { bin = 4u; resid = r - c4; }
        else if (r < c6) { bin = 5u; resid = r - c5; }
        else if (r < c7) { bin = 6u; resid = r - c6; }
        else             { bin = 7u; resid = r - c7; }
        selres[2*j] = 8u * (unsigned)tid + bin; selres[2*j+1] = resid;
      }
    }
  }
  __syncthreads();  // B4: res + selres visible; U[0..383] zeroed

  float SD = res[0], SAD = res[1], SDD = res[2];
  float C2w = res[12];
  float var = C2w / fT;
  float sd = (var > 0.f) ? sqrtf(var) : 0.f;
  float C3 = S3v - 3.f*mean*S2v + 2.f*fT*mean*mean*mean;
  float mm = mean * mean;
  float C4 = S4v - 4.f*mean*S3v + 6.f*mm*S2v - 3.f*fT*mm*mm;
  float skw = (sd > 0.f) ? (fT / ((fT - 1.f) * (fT - 2.f))) * (C3 / (sd * sd * sd)) : 0.f;
  float k22 = C2w * C2w;
  float alphaT = fT * (fT + 1.f) * (fT - 1.f) / ((fT - 2.f) * (fT - 3.f));
  float kurt = ((k22 > 0.f) ? alphaT * C4 / k22 : 0.f)
               - 3.f * (fT - 1.f) * (fT - 1.f) / ((fT - 2.f) * (fT - 3.f));
  float ac[9], acm, acv, acs, ack, acmax;
  {
    float invvar = (var != 0.f) ? 1.f / var : 0.f;
#pragma unroll
    for (int l = 1; l <= 9; l++) ac[l-1] = res[2 + l] / (fT - (float)l) * invvar;
    agg4_9(ac, &acm, &acv, &acs, &ack);
    acmax = ac[0];
#pragma unroll
    for (int l = 1; l < 9; l++) acmax = fmaxf(acmax, ac[l]);
  }
  unsigned int prefix[3], rank[3];
#pragma unroll
  for (int j = 0; j < 3; j++) { prefix[j] = selres[2*j] << 21; rank[j] = selres[2*j+1]; }

  // ---- radix rounds B..D: 7-bit digits, 3 targets, 2 barriers/round ----
#pragma unroll
  for (int rnd = 0; rnd < 3; rnd++) {
    const int shift = 14 - 7 * rnd;
    const int pshift = shift + 7;
#pragma unroll
    for (int k = 0; k < 8; k++) {
      unsigned u = key[k];
      unsigned hi = u >> pshift;
#pragma unroll
      for (int j = 0; j < 3; j++) {
        if (hi == (prefix[j] >> pshift))
          atomicAdd(&U[j * 128 + ((u >> shift) & 127u)], 1u);
      }
    }
    __syncthreads();  // hist done
    if (tid < 192) {
      int j = wave, l = lane;
      unsigned h0v = U[j*128 + 2*l], h1v = U[j*128 + 2*l + 1];
      U[j*128 + 2*l] = 0u; U[j*128 + 2*l + 1] = 0u;  // self-zero for next round
      unsigned tt = h0v + h1v;
      unsigned sc2 = tt;
#pragma unroll
      for (int off = 1; off < 64; off <<= 1) {
        unsigned n = __shfl_up(sc2, off);
        if (l >= off) sc2 += n;
      }
      unsigned ex = sc2 - tt;
      unsigned rj = rank[j];
      if (rj >= ex && rj < ex + tt) {
        if (rj < ex + h0v) { selres[2*j] = 2u*l;     selres[2*j+1] = rj - ex; }
        else               { selres[2*j] = 2u*l + 1u; selres[2*j+1] = rj - ex - h0v; }
      }
    }
    __syncthreads();  // selres + zeroing visible
#pragma unroll
    for (int j = 0; j < 3; j++) { prefix[j] |= selres[2*j] << shift; rank[j] = selres[2*j+1]; }
  }
  float q0 = ord2f(prefix[0]), q1 = ord2f(prefix[1]), q2 = ord2f(prefix[2]);
  float tb0 = a[0], tb1 = a[512], tb2 = a[1024], tb3 = a[1536], tb4 = a[2047];

  // ---- phase 4: count/crossings via integer-domain ballots ----
  {
    const unsigned int kt0 = f2ord(0.f), kt1 = f2ord(mean), kt2 = prefix[0], kt3 = prefix[1], kt4 = prefix[2];
    const unsigned int kt5 = f2ord(tb0), kt6 = f2ord(tb1), kt7 = f2ord(tb2), kt8 = f2ord(tb3), kt9 = f2ord(tb4);
    int cnt0=0,cnt1=0,cnt2=0,cnt3=0,cnt4=0,cnt5=0,cnt6=0,cnt7=0,cnt8=0,cnt9=0;
    int crs0=0,crs1=0,crs2=0,crs3=0,crs4=0,crs5=0,crs6=0,crs7=0,crs8=0,crs9=0;
#pragma unroll
    for (int k = 0; k < 8; k++) {
      unsigned int kv = key[k];
#define BAL(J, KT)                                                        \
      { unsigned long long mp = __ballot(kv > (KT));                      \
        unsigned long long mz = __ballot(kv == (KT));                     \
        cnt##J += (int)__popcll(mp);                                      \
        unsigned long long df = ((mp ^ (mp >> 1)) | (mz ^ (mz >> 1)))     \
                                & 0x7fffffffffffffffull;                  \
        crs##J += (int)__popcll(df); }
      BAL(0, kt0) BAL(1, kt1) BAL(2, kt2) BAL(3, kt3) BAL(4, kt4)
      BAL(5, kt5) BAL(6, kt6) BAL(7, kt7) BAL(8, kt8) BAL(9, kt9)
#undef BAL
    }
    // seam crossings (t = 64m+63, m=0..30), packed 6-bit fields in u64
    if (tid < 64) {
      unsigned long long pk = 0ull;
      if (tid < 31) {
        float a0 = a[64*tid + 63], a1 = a[64*tid + 64];
#define SEAMB(J, TH)                                                      \
        { bool g0 = a0 > (TH), g1 = a1 > (TH);                            \
          bool e0 = a0 == (TH), e1 = a1 == (TH);                          \
          if ((g0 != g1) || (e0 != e1)) pk |= (1ull << (6*(J))); }
        SEAMB(0, 0.f) SEAMB(1, mean) SEAMB(2, q0) SEAMB(3, q1) SEAMB(4, q2)
        SEAMB(5, tb0) SEAMB(6, tb1) SEAMB(7, tb2) SEAMB(8, tb3) SEAMB(9, tb4)
#undef SEAMB
      }
      pk += __shfl_down(pk, 32); pk += __shfl_down(pk, 16); pk += __shfl_down(pk, 8);
      pk += __shfl_down(pk, 4);  pk += __shfl_down(pk, 2);  pk += __shfl_down(pk, 1);
      if (tid == 0) {
#pragma unroll
        for (int j = 0; j < 10; j++) redw[80 + j] = (float)((unsigned int)((pk >> (6*j)) & 63ull));
      }
    }
    if (lane == 0) {
      int w20 = wave * 20;
      redw[w20+0]=(float)cnt0; redw[w20+1]=(float)cnt1; redw[w20+2]=(float)cnt2;
      redw[w20+3]=(float)cnt3; redw[w20+4]=(float)cnt4; redw[w20+5]=(float)cnt5;
      redw[w20+6]=(float)cnt6; redw[w20+7]=(float)cnt7; redw[w20+8]=(float)cnt8;
      redw[w20+9]=(float)cnt9;
      redw[w20+10]=(float)crs0; redw[w20+11]=(float)crs1; redw[w20+12]=(float)crs2;
      redw[w20+13]=(float)crs3; redw[w20+14]=(float)crs4; redw[w20+15]=(float)crs5;
      redw[w20+16]=(float)crs6; redw[w20+17]=(float)crs7; redw[w20+18]=(float)crs8;
      redw[w20+19]=(float)crs9;
    }
  }

  // ---- build 1024-entry twiddle table (cos, -sin of pi*k/1024), XOR-swizzled; U is dead ----
  {
    float cs, sn;
    __sincosf(-PI_F * (float)tid * (1.f / 256.f), &sn, &cs);  // k = 4*tid
    const float cd = 0.9999952938095762f;      // cos(pi/1024)
    const float sd_ = -0.0030679567629659761f; // -sin(pi/1024)
#pragma unroll
    for (int j = 0; j < 4; j++) {
      int k = 4 * tid + j;
      int xk = k ^ (k >> 5);
      Tc[xk] = cs; Ts[xk] = sn;
      float ncs = cs * cd - sn * sd_;
      float nsn = sn * cd + cs * sd_;
      cs = ncs; sn = nsn;
    }
  }

  // ---- read pairs for FFT scramble (a about to be overlaid) ----
  float2 rz0, rz1, rz2, rz3;
  {
    const float2* a2 = (const float2*)a;
    rz0 = a2[tid]; rz1 = a2[tid + 256]; rz2 = a2[tid + 512]; rz3 = a2[tid + 768];
  }
  __syncthreads();  // B: all a[] reads done; table + phase-4 partials written

  // phase-4 combine (into res[4..23], survives to tail)
  if (tid < 20) {
    float s = redw[tid] + redw[20 + tid] + redw[40 + tid] + redw[60 + tid];
    if (tid >= 10) s += redw[80 + (tid - 10)];
    res[4 + tid] = s;
  }
  // scatter step-1 (conflict-free) into zr/zi (overlaying a)
  {
#define SCAT(K, Z)                                                     \
    { int p = tid + (K) * 256;                                         \
      int rl = (int)(__brev((unsigned)(p & 31)) >> 27);                \
      int c = p >> 5;                                                  \
      int idx = rl * 32 + (c ^ rl);                                    \
      zr[idx] = (Z).x; zi[idx] = (Z).y; }
    SCAT(0, rz0) SCAT(1, rz1) SCAT(2, rz2) SCAT(3, rz3)
#undef SCAT
  }
  __syncthreads();
  float gr[4], gi[4];
#pragma unroll
  for (int k = 0; k < 4; k++) {
    int m = tid + k * 256;
    int h = m >> 5, l = m & 31;
    int rl5 = (int)(__brev((unsigned)l) >> 27);
    int idx = h * 32 + (rl5 ^ h);
    gr[k] = zr[idx]; gi[k] = zi[idx];
  }
  __syncthreads();
#pragma unroll
  for (int k = 0; k < 4; k++) { int m = tid + k * 256; zr[m] = gr[k]; zi[m] = gi[k]; }
  __syncthreads();

  // ---- FFT: 1024-pt, radix-4 stages ----
  {  // stage p=0 (thread-local quads)
    float4 R = ((const float4*)zr)[tid];
    float4 I = ((const float4*)zi)[tid];
    float u0r = R.x + R.y, u0i = I.x + I.y;
    float u1r = R.x - R.y, u1i = I.x - I.y;
    float u2r = R.z + R.w, u2i = I.z + I.w;
    float u3r = R.z - R.w, u3i = I.z - I.w;
    float4 Ro, Io;
    Ro.x = u0r + u2r; Io.x = u0i + u2i;
    Ro.z = u0r - u2r; Io.z = u0i - u2i;
    Ro.y = u1r + u3i; Io.y = u1i - u3r;
    Ro.w = u1r - u3i; Io.w = u1i + u3r;
    ((float4*)zr)[tid] = Ro; ((float4*)zi)[tid] = Io;
  }
#pragma unroll
  for (int p = 1; p < 5; p++) {
    const int hf = 1 << (2 * p);
    __syncthreads();
    const int qq = tid & (hf - 1);
    const int i0 = ((tid >> (2 * p)) << (2 * p + 2)) | qq;
    const int i1 = i0 + hf, i2 = i0 + 2 * hf, i3 = i0 + 3 * hf;
    const int t1 = qq << (10 - 2 * p);
    const int t2 = qq << (9 - 2 * p);
    const int t3 = t2 + 512;
    const int x1 = t1 ^ (t1 >> 5), x2 = t2 ^ (t2 >> 5), x3 = t3 ^ (t3 >> 5);
    float cA = Tc[x1], sA = Ts[x1];
    float cB = Tc[x2], sB = Ts[x2];
    float cC = Tc[x3], sC = Ts[x3];
    float r0 = zr[i0], m0 = zi[i0], r1 = zr[i1], m1 = zi[i1];
    float r2 = zr[i2], m2 = zi[i2], r3 = zr[i3], m3 = zi[i3];
    float a1r = cA*r1 - sA*m1, a1i = cA*m1 + sA*r1;
    float a3r = cA*r3 - sA*m3, a3i = cA*m3 + sA*r3;
    float u0r = r0 + a1r, u0i = m0 + a1i;
    float u1r = r0 - a1r, u1i = m0 - a1i;
    float u2r = r2 + a3r, u2i = m2 + a3i;
    float u3r = r2 - a3r, u3i = m2 - a3i;
    float b2r = cB*u2r - sB*u2i, b2i = cB*u2i + sB*u2r;
    float b3r = cC*u3r - sC*u3i, b3i = cC*u3i + sC*u3r;
    zr[i0] = u0r + b2r; zi[i0] = u0i + b2i;
    zr[i2] = u0r - b2r; zi[i2] = u0i - b2i;
    zr[i1] = u1r + b3r; zi[i1] = u1i + b3i;
    zr[i3] = u1r - b3r; zi[i3] = u1i - b3i;
  }
  __syncthreads();

  // ---- untangle + amp/ang (regs) + raw amp power sums ----
  float ampv[4], angv[4];
  float v4[4] = {0.f, 0.f, 0.f, 0.f};
#pragma unroll
  for (int k = 0; k < 4; k++) {
    int kk = tid + k * NTH;
    int nk = (1024 - kk) & 1023;
    float z1r = zr[kk], z1i = zi[kk];
    float z2r = zr[nk], z2i = zi[nk];
    float Er = 0.5f * (z1r + z2r), Ei = 0.5f * (z1i - z2i);
    float Or = 0.5f * (z1i + z2i), Oi = -0.5f * (z1r - z2r);
    int xk = kk ^ (kk >> 5);
    float cs = Tc[xk], sn = Ts[xk];
    float Xr = Er + cs * Or - sn * Oi;
    float Xi = Ei + cs * Oi + sn * Or;
    float amp = sqrtf(Xr * Xr + Xi * Xi);
    ampv[k] = amp;
    angv[k] = fast_atan2f(Xi, Xr);
    float a2p = amp * amp;
    v4[0] += amp; v4[1] += a2p; v4[2] += a2p * amp; v4[3] += a2p * a2p;
  }
  float amp4 = 0.f, ang4 = 0.f;
  if (tid == 0) {  // Nyquist bin 1024
    float Xr = zr[0] - zi[0];
    amp4 = fabsf(Xr);
    ang4 = (Xr < 0.f) ? PI_F : 0.f;
    float a2p = amp4 * amp4;
    v4[0] += amp4; v4[1] += a2p; v4[2] += a2p * amp4; v4[3] += a2p * a2p;
  }
  block_sum_n<4>(v4, redw, res, tid);
  float S = res[0], M2 = res[1], M3 = res[2], M4 = res[3];
  const float fn = 1025.f;
  float am = S / fn;
  float A2 = M2 - fn * am * am;
  float A3 = M3 - 3.f * am * M2 + 2.f * fn * am * am * am;
  float am2 = am * am;
  float A4 = M4 - 4.f * am * M3 + 6.f * am2 * M2 - 3.f * fn * am2 * am2;
  float av = A2 / fn;
  float asd = (av > 0.f) ? sqrtf(av) : 0.f;
  float ask = (asd > 0.f) ? fn / ((fn - 1.f) * (fn - 2.f)) * (A3 / (asd * asd * asd)) : 0.f;
  float ak22 = A2 * A2;
  float aal = fn * (fn + 1.f) * (fn - 1.f) / ((fn - 2.f) * (fn - 3.f));
  float aku = ((ak22 > 0.f) ? aal * A4 / ak22 : 0.f)
              - 3.f * (fn - 1.f) * (fn - 1.f) / ((fn - 2.f) * (fn - 3.f));
  float invS = (S != 0.f) ? 1.f / S : 0.f;
  float rm = am * invS;
  float rv = av * invS * invS;

  // ---- barrier-free tail: all global stores ----
#pragma unroll
  for (int k = 0; k < 4; k++) {
    int kk = tid + k * NTH;
    op[53 + kk]   = ampv[k];
    op[1078 + kk] = angv[k];
    op[2103 + kk] = ampv[k] * invS;
  }
  if (tid < 9) {
    float acj;
    switch (tid) {
      case 0: acj = ac[0]; break; case 1: acj = ac[1]; break; case 2: acj = ac[2]; break;
      case 3: acj = ac[3]; break; case 4: acj = ac[4]; break; case 5: acj = ac[5]; break;
      case 6: acj = ac[6]; break; case 7: acj = ac[7]; break; default: acj = ac[8]; break;
    }
    op[3128 + tid] = acj;
    op[3137 + tid] = (acmax != 0.f) ? acj / acmax : 0.f;
  }
  if (tid == 0) {
    op[53 + 1024] = amp4; op[1078 + 1024] = ang4; op[2103 + 1024] = amp4 * invS;
    op[0] = mean; op[1] = MN; op[2] = MX; op[3] = rms; op[4] = var; op[5] = sd;
    op[6] = skw; op[7] = kurt;
    op[8] = SD / (fT - 2.f); op[9] = SD; op[10] = SAD / (fT - 2.f);
    op[11] = S2v; op[12] = maxabs; op[13] = SAD;
    op[14] = (SDD > 0.f) ? sqrtf(SDD) : 0.f;
    op[15] = res[4]; op[16] = res[5];
    op[17] = res[9]; op[18] = res[10]; op[19] = res[11]; op[20] = res[12]; op[21] = res[13];
    op[22] = res[14]; op[23] = res[15];
    op[24] = res[16]; op[25] = res[17]; op[26] = res[18];
    op[27] = res[19]; op[28] = res[20]; op[29] = res[21]; op[30] = res[22]; op[31] = res[23];
    op[32] = ampv[0];
    op[33] = am; op[34] = av; op[35] = ask; op[36] = aku;
    op[37] = rm; op[38] = rv; op[39] = ask; op[40] = aku;
    op[41] = acm; op[42] = acv; op[43] = acs; op[44] = ack;
    op[45] = q0; op[46] = q1; op[47] = q2;
    op[48] = tb0; op[49] = tb1; op[50] = tb2; op[51] = tb3; op[52] = tb4;
  }
}

extern "C" void kernel_launch(void* const* d_in, const int* in_sizes, int n_in,
                              void* d_out, int out_size, void* d_ws, size_t ws_size,
                              hipStream_t stream) {
  const float* x = (const float*)d_in[0];
  float* out = (float*)d_out;
  const int total = in_sizes[0];
  const int B = total / (T_LEN * NF);
  const int nblocks = B * NF;
  const int gpx = (B % 8 == 0) ? (B / 8) : 0;
  ts_feat_kernel<<<nblocks, NTH, 0, stream>>>(x, out, gpx);
}

// Round 8
// 202.818 us; speedup vs baseline: 1.0538x; 1.0538x over previous
//
#include <hip/hip_runtime.h>
#include <math.h>

#define T_LEN 2048
#define NF    16
#define NTH   256
#define NOUT  3146
#define PI_F  3.14159265358979323846f

// zr/zi physical index swizzle: spreads FFT stage-1/2 strided accesses across banks.
// Touches only bits 2-4 -> float4 quads (low 2 bits) preserved.
#define ZPHYS(i) ((i) ^ ((((i) >> 5) & 7) << 2))

// ---------------- wave reductions (wave = 64) ----------------
__device__ __forceinline__ float wred_sum(float v) {
  v += __shfl_down(v, 32); v += __shfl_down(v, 16); v += __shfl_down(v, 8);
  v += __shfl_down(v, 4);  v += __shfl_down(v, 2);  v += __shfl_down(v, 1);
  return v;
}
__device__ __forceinline__ float wred_min(float v) {
  v = fminf(v, __shfl_down(v, 32)); v = fminf(v, __shfl_down(v, 16)); v = fminf(v, __shfl_down(v, 8));
  v = fminf(v, __shfl_down(v, 4));  v = fminf(v, __shfl_down(v, 2));  v = fminf(v, __shfl_down(v, 1));
  return v;
}
__device__ __forceinline__ float wred_max(float v) {
  v = fmaxf(v, __shfl_down(v, 32)); v = fmaxf(v, __shfl_down(v, 16)); v = fmaxf(v, __shfl_down(v, 8));
  v = fmaxf(v, __shfl_down(v, 4));  v = fmaxf(v, __shfl_down(v, 2));  v = fmaxf(v, __shfl_down(v, 1));
  return v;
}

// batched block sum: N values, 2 barriers total
template<int N>
__device__ __forceinline__ void block_sum_n(float (&v)[N], float* redw, float* res, int tid) {
  const int wave = tid >> 6;
#pragma unroll
  for (int j = 0; j < N; j++) {
    float s = wred_sum(v[j]);
    if ((tid & 63) == 0) redw[j * 4 + wave] = s;
  }
  __syncthreads();
  if (tid < N) res[tid] = redw[tid * 4] + redw[tid * 4 + 1] + redw[tid * 4 + 2] + redw[tid * 4 + 3];
  __syncthreads();
}

// agg4 over 9 register values
__device__ __forceinline__ void agg4_9(const float* v, float* om, float* ov, float* os, float* ok) {
  const float fn = 9.0f;
  float s = 0.f;
#pragma unroll
  for (int i = 0; i < 9; i++) s += v[i];
  float m = s / fn;
  float c2 = 0.f, c3 = 0.f, c4 = 0.f;
#pragma unroll
  for (int i = 0; i < 9; i++) {
    float c = v[i] - m; float cc = c * c;
    c2 += cc; c3 += cc * c; c4 += cc * cc;
  }
  float var = c2 / fn;
  float sd = (var > 0.f) ? sqrtf(var) : 0.f;
  float sk = (sd > 0.f) ? fn / ((fn - 1.f) * (fn - 2.f)) * (c3 / (sd * sd * sd)) : 0.f;
  float k22 = c2 * c2;
  float al = fn * (fn + 1.f) * (fn - 1.f) / ((fn - 2.f) * (fn - 3.f));
  float ku = ((k22 > 0.f) ? al * c4 / k22 : 0.f)
             - 3.f * (fn - 1.f) * (fn - 1.f) / ((fn - 2.f) * (fn - 3.f));
  *om = m; *ov = var; *os = sk; *ok = ku;
}

__device__ __forceinline__ float ord2f(unsigned int u) {
  unsigned int v = (u & 0x80000000u) ? (u ^ 0x80000000u) : ~u;
  return __uint_as_float(v);
}
__device__ __forceinline__ unsigned int f2ord(float v) {
  unsigned int u = __float_as_uint(v);
  return (u & 0x80000000u) ? ~u : (u | 0x80000000u);
}

// fast atan2 (deg-2 poly, max err ~0.006 rad; output threshold is 50.24 absolute)
__device__ __forceinline__ float fast_atan2f(float y, float x) {
  float ay = fabsf(y), ax = fabsf(x);
  float mx = fmaxf(ax, ay), mn = fminf(ax, ay);
  if (mx == 0.f) return 0.f;
  float t = __fdividef(mn, mx);
  float s = t * t;
  float p = fmaf(s, fmaf(s, 0.079331f, -0.288679f), 0.995354f);
  float r = t * p;
  if (ay > ax) r = 1.57079632679f - r;
  if (x < 0.f) r = PI_F - r;
  return (y < 0.f) ? -r : r;
}

__global__ __launch_bounds__(NTH)
void ts_feat_kernel(const float* __restrict__ x, float* __restrict__ out, int gpx) {
  __shared__ __align__(16) float a[T_LEN];        // series; later zr=a[0..1023], zi=a[1024..2047]
  __shared__ __align__(16) unsigned int U[2048];  // radix hists/cums; later cos[1024]+sin[1024]
  __shared__ float redw[96];
  __shared__ float res[24];
  __shared__ unsigned int selres[8];

  float* zr = a;
  float* zi = a + 1024;
  float* Tc = (float*)U;
  float* Ts = (float*)U + 1024;

  const int tid = threadIdx.x;
  const int lane = tid & 63;
  const int wave = tid >> 6;
  int b, f;
  {
    int i = blockIdx.x;
    if (gpx > 0) { int xc = i & 7; int slot = i >> 3; b = xc * gpx + (slot >> 4); f = slot & 15; }
    else { b = i >> 4; f = i & 15; }
  }
  const float* xp = x + ((size_t)b * T_LEN) * NF + f;
  float* op = out + (size_t)(b * NF + f) * NOUT;
  const float fT = (float)T_LEN;

  // ---- zero round-A hist+cums [0..1279] ----
#pragma unroll
  for (int k = 0; k < 5; k++) U[tid + k * NTH] = 0u;

  // ---- phase 1: load; raw power sums; min/max; keys ----
  unsigned int key[8];
  float s1 = 0.f, s2 = 0.f, s3 = 0.f, s4 = 0.f, mn = 3.4e38f, mx = -3.4e38f;
#pragma unroll
  for (int k = 0; k < 8; k++) {
    int t = tid + k * NTH;
    float v = xp[(size_t)t * NF];
    a[t] = v;
    key[k] = f2ord(v);
    float v2 = v * v;
    s1 += v; s2 += v2; s3 += v2 * v; s4 += v2 * v2;
    mn = fminf(mn, v); mx = fmaxf(mx, v);
  }
  s1 = wred_sum(s1); s2 = wred_sum(s2); s3 = wred_sum(s3); s4 = wred_sum(s4);
  mn = wred_min(mn); mx = wred_max(mx);
  if (lane == 0) {
    redw[wave] = s1; redw[4 + wave] = s2; redw[8 + wave] = s3; redw[12 + wave] = s4;
    redw[16 + wave] = mn; redw[20 + wave] = mx;
  }
  __syncthreads();  // B1: U zeroed, a[] written, redw partials

  // round-A histogram (fused) + stat combine
  const int woff = wave << 8;
#pragma unroll
  for (int k = 0; k < 8; k++) atomicAdd(&U[woff + (key[k] >> 24)], 1u);
  if (tid == 0) {
    res[0] = redw[0] + redw[1] + redw[2] + redw[3];
    res[1] = redw[4] + redw[5] + redw[6] + redw[7];
    res[2] = redw[8] + redw[9] + redw[10] + redw[11];
    res[3] = redw[12] + redw[13] + redw[14] + redw[15];
    res[4] = fminf(fminf(redw[16], redw[17]), fminf(redw[18], redw[19]));
    res[5] = fmaxf(fmaxf(redw[20], redw[21]), fmaxf(redw[22], redw[23]));
  }
  __syncthreads();  // B2: atomics done; stats visible

  float S1 = res[0], S2v = res[1], S3v = res[2], S4v = res[3], MN = res[4], MX = res[5];
  float mean = S1 / fT;
  float maxabs = fmaxf(-MN, MX);
  float rms = sqrtf(fmaxf(S2v / fT, 0.f));

  // round-A scan (wave 0, no internal sync)
  if (tid < 64) {
    const int l = tid;
    unsigned int b0 = U[4*l]   + U[256+4*l]   + U[512+4*l]   + U[768+4*l];
    unsigned int b1 = U[4*l+1] + U[256+4*l+1] + U[512+4*l+1] + U[768+4*l+1];
    unsigned int b2 = U[4*l+2] + U[256+4*l+2] + U[512+4*l+2] + U[768+4*l+2];
    unsigned int b3 = U[4*l+3] + U[256+4*l+3] + U[512+4*l+3] + U[768+4*l+3];
    unsigned int t0 = b0, t1 = t0 + b1, t2 = t1 + b2, t3 = t2 + b3;
    unsigned int tot = t3;
#pragma unroll
    for (int off = 1; off < 64; off <<= 1) {
      unsigned int n = __shfl_up(tot, off);
      if (l >= off) tot += n;
    }
    unsigned int base0 = tot - t3;
    U[1024+4*l] = base0+t0; U[1024+4*l+1] = base0+t1; U[1024+4*l+2] = base0+t2; U[1024+4*l+3] = base0+t3;
  }

  // phase-2 window: diffs + lags + window-C2 (ac path kept bit-identical to r5/r6)
  float v13[13];
  {
    const int base = tid * 8;
    const float4* a4 = (const float4*)a;
    float4 w0 = a4[tid*2], w1 = a4[tid*2+1];
    int i2 = (base + 11 < T_LEN) ? tid*2+2 : 0;
    int i3 = (base + 15 < T_LEN) ? tid*2+3 : 0;
    float4 w2 = a4[i2], w3 = a4[i3];
    bool ok2 = (base + 11 < T_LEN), ok3 = (base + 15 < T_LEN);
    float r[17];
    r[0]=w0.x; r[1]=w0.y; r[2]=w0.z; r[3]=w0.w;
    r[4]=w1.x; r[5]=w1.y; r[6]=w1.z; r[7]=w1.w;
    r[8]  = ok2 ? w2.x : mean; r[9]  = ok2 ? w2.y : mean; r[10] = ok2 ? w2.z : mean; r[11] = ok2 ? w2.w : mean;
    r[12] = ok3 ? w3.x : mean; r[13] = ok3 ? w3.y : mean; r[14] = ok3 ? w3.z : mean; r[15] = ok3 ? w3.w : mean;
    r[16] = (base + 16 < T_LEN) ? a[base + 16] : mean;
    float cw[17];
#pragma unroll
    for (int j = 0; j < 17; j++) cw[j] = r[j] - mean;
#pragma unroll
    for (int j = 0; j < 13; j++) v13[j] = 0.f;
#pragma unroll
    for (int j = 0; j < 8; j++) {
      if (base + j < T_LEN - 2) {
        float d = r[j+1] - r[j+2];
        v13[0] += d; v13[1] += fabsf(d); v13[2] += d * d;
      }
    }
#pragma unroll
    for (int l = 1; l <= 9; l++) {
#pragma unroll
      for (int j = 0; j < 8; j++) {
        v13[2 + l] += cw[j] * cw[j + l];  // OOB cw == 0
      }
    }
#pragma unroll
    for (int j = 0; j < 8; j++) v13[12] += cw[j] * cw[j];
  }
  __syncthreads();  // B3: scan-A cums visible

  // pick-A (all 256 bins) + zero U[0..767] for round B
  unsigned int prefix[3];
  unsigned int rank[3];
  {
    unsigned int incl = U[1024 + tid];
    unsigned int excl = (tid == 0) ? 0u : U[1024 + tid - 1];
    const unsigned int rks[3] = {512u, 1024u, 1536u};
#pragma unroll
    for (int j = 0; j < 3; j++)
      if (excl <= rks[j] && rks[j] < incl) { selres[2*j] = (unsigned)tid; selres[2*j+1] = rks[j] - excl; }
    U[tid] = 0u; U[tid + 256] = 0u; U[tid + 512] = 0u;
  }

  block_sum_n<13>(v13, redw, res, tid);  // B4, B5
  float SD = res[0], SAD = res[1], SDD = res[2];
  float C2w = res[12];
  float var = C2w / fT;
  float sd = (var > 0.f) ? sqrtf(var) : 0.f;
  float C3 = S3v - 3.f*mean*S2v + 2.f*fT*mean*mean*mean;
  float mm = mean * mean;
  float C4 = S4v - 4.f*mean*S3v + 6.f*mm*S2v - 3.f*fT*mm*mm;
  float skw = (sd > 0.f) ? (fT / ((fT - 1.f) * (fT - 2.f))) * (C3 / (sd * sd * sd)) : 0.f;
  float k22 = C2w * C2w;
  float alphaT = fT * (fT + 1.f) * (fT - 1.f) / ((fT - 2.f) * (fT - 3.f));
  float kurt = ((k22 > 0.f) ? alphaT * C4 / k22 : 0.f)
               - 3.f * (fT - 1.f) * (fT - 1.f) / ((fT - 2.f) * (fT - 3.f));
  float ac[9], acm, acv, acs, ack, acmax;
  {
    float invvar = (var != 0.f) ? 1.f / var : 0.f;
#pragma unroll
    for (int l = 1; l <= 9; l++) ac[l-1] = res[2 + l] / (fT - (float)l) * invvar;
    agg4_9(ac, &acm, &acv, &acs, &ack);
    acmax = ac[0];
#pragma unroll
    for (int l = 1; l < 9; l++) acmax = fmaxf(acmax, ac[l]);
  }
#pragma unroll
  for (int j = 0; j < 3; j++) { prefix[j] = selres[2*j] << 24; rank[j] = selres[2*j+1]; }

  // ---- radix rounds B..D: 3 targets concurrently, 3 barriers each ----
  for (int rnd = 1; rnd < 4; rnd++) {
    const int shift = 24 - 8 * rnd;
#pragma unroll
    for (int k = 0; k < 8; k++) {
      unsigned int u = key[k];
      unsigned int hi = u >> (shift + 8);
#pragma unroll
      for (int j = 0; j < 3; j++) {
        if (hi == (prefix[j] >> (shift + 8)))
          atomicAdd(&U[j * 256 + ((u >> shift) & 255u)], 1u);
      }
    }
    __syncthreads();  // hist done
    if (tid < 192) {
      int w = tid >> 6, l = tid & 63;
      unsigned int* h = U + w * 256;
      unsigned int b0 = h[4*l], b1 = h[4*l+1], b2 = h[4*l+2], b3 = h[4*l+3];
      unsigned int t0 = b0, t1 = t0+b1, t2 = t1+b2, t3 = t2+b3;
      unsigned int tot = t3;
#pragma unroll
      for (int off = 1; off < 64; off <<= 1) {
        unsigned int n = __shfl_up(tot, off);
        if (l >= off) tot += n;
      }
      unsigned int base0 = tot - t3;
      unsigned int* c = U + 768 + w * 256;
      c[4*l] = base0+t0; c[4*l+1] = base0+t1; c[4*l+2] = base0+t2; c[4*l+3] = base0+t3;
    }
    __syncthreads();  // cums visible
    if (tid < 192) {
      int j = tid >> 6, l = tid & 63;
#pragma unroll
      for (int i = 0; i < 4; i++) {
        int bk = 4 * l + i;
        unsigned int incl = U[768 + j * 256 + bk];
        unsigned int excl = (bk == 0) ? 0u : U[768 + j * 256 + bk - 1];
        if (excl <= rank[j] && rank[j] < incl) { selres[2*j] = (unsigned)bk; selres[2*j+1] = rank[j] - excl; }
      }
    } else if (rnd < 3) {
      int z0 = (tid - 192) * 12;
#pragma unroll
      for (int k = 0; k < 12; k++) U[z0 + k] = 0u;
    }
    __syncthreads();
#pragma unroll
    for (int j = 0; j < 3; j++) { prefix[j] |= selres[2*j] << shift; rank[j] = selres[2*j+1]; }
  }
  float q0 = ord2f(prefix[0]), q1 = ord2f(prefix[1]), q2 = ord2f(prefix[2]);
  float tb0 = a[0], tb1 = a[512], tb2 = a[1024], tb3 = a[1536], tb4 = a[2047];

  // ---- phase 4: count/crossings via integer-domain ballots ----
  {
    const unsigned int kt0 = f2ord(0.f), kt1 = f2ord(mean), kt2 = prefix[0], kt3 = prefix[1], kt4 = prefix[2];
    const unsigned int kt5 = f2ord(tb0), kt6 = f2ord(tb1), kt7 = f2ord(tb2), kt8 = f2ord(tb3), kt9 = f2ord(tb4);
    int cnt0=0,cnt1=0,cnt2=0,cnt3=0,cnt4=0,cnt5=0,cnt6=0,cnt7=0,cnt8=0,cnt9=0;
    int crs0=0,crs1=0,crs2=0,crs3=0,crs4=0,crs5=0,crs6=0,crs7=0,crs8=0,crs9=0;
#pragma unroll
    for (int k = 0; k < 8; k++) {
      unsigned int kv = key[k];
#define BAL(J, KT)                                                        \
      { unsigned long long mp = __ballot(kv > (KT));                      \
        unsigned long long mz = __ballot(kv == (KT));                     \
        cnt##J += (int)__popcll(mp);                                      \
        unsigned long long df = ((mp ^ (mp >> 1)) | (mz ^ (mz >> 1)))     \
                                & 0x7fffffffffffffffull;                  \
        crs##J += (int)__popcll(df); }
      BAL(0, kt0) BAL(1, kt1) BAL(2, kt2) BAL(3, kt3) BAL(4, kt4)
      BAL(5, kt5) BAL(6, kt6) BAL(7, kt7) BAL(8, kt8) BAL(9, kt9)
#undef BAL
    }
    // seam crossings (t = 64m+63, m=0..30), packed 6-bit fields in u64
    if (tid < 64) {
      unsigned long long pk = 0ull;
      if (tid < 31) {
        float a0 = a[64*tid + 63], a1 = a[64*tid + 64];
#define SEAMB(J, TH)                                                      \
        { bool g0 = a0 > (TH), g1 = a1 > (TH);                            \
          bool e0 = a0 == (TH), e1 = a1 == (TH);                          \
          if ((g0 != g1) || (e0 != e1)) pk |= (1ull << (6*(J))); }
        SEAMB(0, 0.f) SEAMB(1, mean) SEAMB(2, q0) SEAMB(3, q1) SEAMB(4, q2)
        SEAMB(5, tb0) SEAMB(6, tb1) SEAMB(7, tb2) SEAMB(8, tb3) SEAMB(9, tb4)
#undef SEAMB
      }
      pk += __shfl_down(pk, 32); pk += __shfl_down(pk, 16); pk += __shfl_down(pk, 8);
      pk += __shfl_down(pk, 4);  pk += __shfl_down(pk, 2);  pk += __shfl_down(pk, 1);
      if (tid == 0) {
#pragma unroll
        for (int j = 0; j < 10; j++) redw[80 + j] = (float)((unsigned int)((pk >> (6*j)) & 63ull));
      }
    }
    if (lane == 0) {
      int w20 = wave * 20;
      redw[w20+0]=(float)cnt0; redw[w20+1]=(float)cnt1; redw[w20+2]=(float)cnt2;
      redw[w20+3]=(float)cnt3; redw[w20+4]=(float)cnt4; redw[w20+5]=(float)cnt5;
      redw[w20+6]=(float)cnt6; redw[w20+7]=(float)cnt7; redw[w20+8]=(float)cnt8;
      redw[w20+9]=(float)cnt9;
      redw[w20+10]=(float)crs0; redw[w20+11]=(float)crs1; redw[w20+12]=(float)crs2;
      redw[w20+13]=(float)crs3; redw[w20+14]=(float)crs4; redw[w20+15]=(float)crs5;
      redw[w20+16]=(float)crs6; redw[w20+17]=(float)crs7; redw[w20+18]=(float)crs8;
      redw[w20+19]=(float)crs9;
    }
  }

  // ---- build 1024-entry twiddle table (cos, -sin of pi*k/1024), XOR-swizzled; U is dead ----
  {
    float cs, sn;
    __sincosf(-PI_F * (float)tid * (1.f / 256.f), &sn, &cs);  // k = 4*tid
    const float cd = 0.9999952938095762f;      // cos(pi/1024)
    const float sd_ = -0.0030679567629659761f; // -sin(pi/1024)
#pragma unroll
    for (int j = 0; j < 4; j++) {
      int k = 4 * tid + j;
      int xk = k ^ (k >> 5);
      Tc[xk] = cs; Ts[xk] = sn;
      float ncs = cs * cd - sn * sd_;
      float nsn = sn * cd + cs * sd_;
      cs = ncs; sn = nsn;
    }
  }

  // ---- read pairs for FFT scramble (a about to be overlaid) ----
  float2 rz0, rz1, rz2, rz3;
  {
    const float2* a2 = (const float2*)a;
    rz0 = a2[tid]; rz1 = a2[tid + 256]; rz2 = a2[tid + 512]; rz3 = a2[tid + 768];
  }
  __syncthreads();  // B: all a[] reads done; table + phase-4 partials written

  // phase-4 combine (into res[4..23], survives to tail)
  if (tid < 20) {
    float s = redw[tid] + redw[20 + tid] + redw[40 + tid] + redw[60 + tid];
    if (tid >= 10) s += redw[80 + (tid - 10)];
    res[4 + tid] = s;
  }
  // scatter step-1 (conflict-free) into zr/zi (overlaying a), ZPHYS layout
  {
#define SCAT(K, Z)                                                     \
    { int p = tid + (K) * 256;                                         \
      int rl = (int)(__brev((unsigned)(p & 31)) >> 27);                \
      int c = p >> 5;                                                  \
      int idx = rl * 32 + (c ^ rl);                                    \
      int px = ZPHYS(idx);                                             \
      zr[px] = (Z).x; zi[px] = (Z).y; }
    SCAT(0, rz0) SCAT(1, rz1) SCAT(2, rz2) SCAT(3, rz3)
#undef SCAT
  }
  __syncthreads();
  float gr[4], gi[4];
#pragma unroll
  for (int k = 0; k < 4; k++) {
    int m = tid + k * 256;
    int h = m >> 5, l = m & 31;
    int rl5 = (int)(__brev((unsigned)l) >> 27);
    int idx = h * 32 + (rl5 ^ h);
    int px = ZPHYS(idx);
    gr[k] = zr[px]; gi[k] = zi[px];
  }
  __syncthreads();
#pragma unroll
  for (int k = 0; k < 4; k++) {
    int m = tid + k * 256;
    int px = ZPHYS(m);
    zr[px] = gr[k]; zi[px] = gi[k];
  }
  __syncthreads();

  // ---- FFT: 1024-pt, radix-4 stages (ZPHYS layout) ----
  {  // stage p=0 (thread-local quads; ZPHYS keeps quads contiguous & aligned)
    int qt = tid ^ ((tid >> 3) & 7);  // float4 index: ZPHYS(4*tid)/4
    float4 R = ((const float4*)zr)[qt];
    float4 I = ((const float4*)zi)[qt];
    float u0r = R.x + R.y, u0i = I.x + I.y;
    float u1r = R.x - R.y, u1i = I.x - I.y;
    float u2r = R.z + R.w, u2i = I.z + I.w;
    float u3r = R.z - R.w, u3i = I.z - I.w;
    float4 Ro, Io;
    Ro.x = u0r + u2r; Io.x = u0i + u2i;
    Ro.z = u0r - u2r; Io.z = u0i - u2i;
    Ro.y = u1r + u3i; Io.y = u1i - u3r;
    Ro.w = u1r - u3i; Io.w = u1i + u3r;
    ((float4*)zr)[qt] = Ro; ((float4*)zi)[qt] = Io;
  }
#pragma unroll
  for (int p = 1; p < 5; p++) {
    const int hf = 1 << (2 * p);
    __syncthreads();
    const int qq = tid & (hf - 1);
    const int i0 = ((tid >> (2 * p)) << (2 * p + 2)) | qq;
    const int i1 = i0 + hf, i2 = i0 + 2 * hf, i3 = i0 + 3 * hf;
    const int p0 = ZPHYS(i0), p1 = ZPHYS(i1), p2x = ZPHYS(i2), p3x = ZPHYS(i3);
    const int t1 = qq << (10 - 2 * p);
    const int t2 = qq << (9 - 2 * p);
    const int t3 = t2 + 512;
    const int x1 = t1 ^ (t1 >> 5), x2 = t2 ^ (t2 >> 5), x3 = t3 ^ (t3 >> 5);
    float cA = Tc[x1], sA = Ts[x1];
    float cB = Tc[x2], sB = Ts[x2];
    float cC = Tc[x3], sC = Ts[x3];
    float r0 = zr[p0], m0 = zi[p0], r1 = zr[p1], m1 = zi[p1];
    float r2 = zr[p2x], m2 = zi[p2x], r3 = zr[p3x], m3 = zi[p3x];
    float a1r = cA*r1 - sA*m1, a1i = cA*m1 + sA*r1;
    float a3r = cA*r3 - sA*m3, a3i = cA*m3 + sA*r3;
    float u0r = r0 + a1r, u0i = m0 + a1i;
    float u1r = r0 - a1r, u1i = m0 - a1i;
    float u2r = r2 + a3r, u2i = m2 + a3i;
    float u3r = r2 - a3r, u3i = m2 - a3i;
    float b2r = cB*u2r - sB*u2i, b2i = cB*u2i + sB*u2r;
    float b3r = cC*u3r - sC*u3i, b3i = cC*u3i + sC*u3r;
    zr[p0] = u0r + b2r; zi[p0] = u0i + b2i;
    zr[p2x] = u0r - b2r; zi[p2x] = u0i - b2i;
    zr[p1] = u1r + b3r; zi[p1] = u1i + b3i;
    zr[p3x] = u1r - b3r; zi[p3x] = u1i - b3i;
  }
  __syncthreads();

  // ---- untangle + amp/ang (regs) + raw amp power sums ----
  float ampv[4], angv[4];
  float v4[4] = {0.f, 0.f, 0.f, 0.f};
#pragma unroll
  for (int k = 0; k < 4; k++) {
    int kk = tid + k * NTH;
    int nk = (1024 - kk) & 1023;
    int pk_ = ZPHYS(kk), pn_ = ZPHYS(nk);
    float z1r = zr[pk_], z1i = zi[pk_];
    float z2r = zr[pn_], z2i = zi[pn_];
    float Er = 0.5f * (z1r + z2r), Ei = 0.5f * (z1i - z2i);
    float Or = 0.5f * (z1i + z2i), Oi = -0.5f * (z1r - z2r);
    int xk = kk ^ (kk >> 5);
    float cs = Tc[xk], sn = Ts[xk];
    float Xr = Er + cs * Or - sn * Oi;
    float Xi = Ei + cs * Oi + sn * Or;
    float amp = sqrtf(Xr * Xr + Xi * Xi);
    ampv[k] = amp;
    angv[k] = fast_atan2f(Xi, Xr);
    float a2p = amp * amp;
    v4[0] += amp; v4[1] += a2p; v4[2] += a2p * amp; v4[3] += a2p * a2p;
  }
  float amp4 = 0.f, ang4 = 0.f;
  if (tid == 0) {  // Nyquist bin 1024 (ZPHYS(0)==0)
    float Xr = zr[0] - zi[0];
    amp4 = fabsf(Xr);
    ang4 = (Xr < 0.f) ? PI_F : 0.f;
    float a2p = amp4 * amp4;
    v4[0] += amp4; v4[1] += a2p; v4[2] += a2p * amp4; v4[3] += a2p * a2p;
  }
  block_sum_n<4>(v4, redw, res, tid);
  float S = res[0], M2 = res[1], M3 = res[2], M4 = res[3];
  const float fn = 1025.f;
  float am = S / fn;
  float A2 = M2 - fn * am * am;
  float A3 = M3 - 3.f * am * M2 + 2.f * fn * am * am * am;
  float am2 = am * am;
  float A4 = M4 - 4.f * am * M3 + 6.f * am2 * M2 - 3.f * fn * am2 * am2;
  float av = A2 / fn;
  float asd = (av > 0.f) ? sqrtf(av) : 0.f;
  float ask = (asd > 0.f) ? fn / ((fn - 1.f) * (fn - 2.f)) * (A3 / (asd * asd * asd)) : 0.f;
  float ak22 = A2 * A2;
  float aal = fn * (fn + 1.f) * (fn - 1.f) / ((fn - 2.f) * (fn - 3.f));
  float aku = ((ak22 > 0.f) ? aal * A4 / ak22 : 0.f)
              - 3.f * (fn - 1.f) * (fn - 1.f) / ((fn - 2.f) * (fn - 3.f));
  float invS = (S != 0.f) ? 1.f / S : 0.f;
  float rm = am * invS;
  float rv = av * invS * invS;

  // ---- barrier-free tail: all global stores ----
#pragma unroll
  for (int k = 0; k < 4; k++) {
    int kk = tid + k * NTH;
    op[53 + kk]   = ampv[k];
    op[1078 + kk] = angv[k];
    op[2103 + kk] = ampv[k] * invS;
  }
  if (tid < 9) {
    float acj;
    switch (tid) {
      case 0: acj = ac[0]; break; case 1: acj = ac[1]; break; case 2: acj = ac[2]; break;
      case 3: acj = ac[3]; break; case 4: acj = ac[4]; break; case 5: acj = ac[5]; break;
      case 6: acj = ac[6]; break; case 7: acj = ac[7]; break; default: acj = ac[8]; break;
    }
    op[3128 + tid] = acj;
    op[3137 + tid] = (acmax != 0.f) ? acj / acmax : 0.f;
  }
  if (tid == 0) {
    op[53 + 1024] = amp4; op[1078 + 1024] = ang4; op[2103 + 1024] = amp4 * invS;
    op[0] = mean; op[1] = MN; op[2] = MX; op[3] = rms; op[4] = var; op[5] = sd;
    op[6] = skw; op[7] = kurt;
    op[8] = SD / (fT - 2.f); op[9] = SD; op[10] = SAD / (fT - 2.f);
    op[11] = S2v; op[12] = maxabs; op[13] = SAD;
    op[14] = (SDD > 0.f) ? sqrtf(SDD) : 0.f;
    op[15] = res[4]; op[16] = res[5];
    op[17] = res[9]; op[18] = res[10]; op[19] = res[11]; op[20] = res[12]; op[21] = res[13];
    op[22] = res[14]; op[23] = res[15];
    op[24] = res[16]; op[25] = res[17]; op[26] = res[18];
    op[27] = res[19]; op[28] = res[20]; op[29] = res[21]; op[30] = res[22]; op[31] = res[23];
    op[32] = ampv[0];
    op[33] = am; op[34] = av; op[35] = ask; op[36] = aku;
    op[37] = rm; op[38] = rv; op[39] = ask; op[40] = aku;
    op[41] = acm; op[42] = acv; op[43] = acs; op[44] = ack;
    op[45] = q0; op[46] = q1; op[47] = q2;
    op[48] = tb0; op[49] = tb1; op[50] = tb2; op[51] = tb3; op[52] = tb4;
  }
}

extern "C" void kernel_launch(void* const* d_in, const int* in_sizes, int n_in,
                              void* d_out, int out_size, void* d_ws, size_t ws_size,
                              hipStream_t stream) {
  const float* x = (const float*)d_in[0];
  float* out = (float*)d_out;
  const int total = in_sizes[0];
  const int B = total / (T_LEN * NF);
  const int nblocks = B * NF;
  const int gpx = (B % 8 == 0) ? (B / 8) : 0;
  ts_feat_kernel<<<nblocks, NTH, 0, stream>>>(x, out, gpx);
}